// Round 9
// baseline (60.000 us; speedup 1.0000x reference)
//
#include <hip/hip_runtime.h>

// Problem constants (from reference): B=16, L=4096, D=1024, K=64
#define Bn 16
#define Ln 4096
#define Dn 1024
#define Kn 64
#define CH 16                  // tokens per fine chunk (slot granularity)
#define SEGTOK 32              // tokens per segment (one stream block)
#define CPS (SEGTOK / CH)      // 2 chunks per segment
#define NSEG (Ln / SEGTOK)     // 128 segments per batch row
#define SLOTS (CPS + 1)        // 3 slots: excl prefix at chunk j, slot 2 = seg total
#define NSPAN (2 * Bn * Kn)    // 2048 span ints

static __device__ __forceinline__ void acc4(float4& a, const float4 v) {
    a.x += v.x; a.y += v.y; a.z += v.z; a.w += v.w;
}
static __device__ __forceinline__ void sub4(float4& a, const float4 v) {
    a.x -= v.x; a.y -= v.y; a.z -= v.z; a.w -= v.w;
}
static __device__ __forceinline__ void acc4w(float4& a, const float4 v, float w) {
    a.x += v.x * w; a.y += v.y * w; a.z += v.z * w; a.w += v.w * w;
}

// ---------------------------------------------------------------------------
// K1 (fused stream + scan, zero-weight rows SKIPPED): grid = B*NSEG segment
// blocks + B am-prefix blocks + 1 decode block.
//  - segment blocks: stream the ATTENDED rows (am!=0, ~50%) of 32 tokens of
//    one (b,seg); running weighted sum written as exclusive intra-segment
//    prefix every 16 tokens (slots 0..1) + segment total (slot 2).
//    2048 blocks = 8/CU = 8 waves/SIMD -> enough TLP to hide the
//    latency of the data-dependent conditional row loads.
//  - am-prefix blocks: exclusive token prefix of attention_mask per batch.
//  - decode block: canonicalize sent_spans to int32 (int64 layout detect).
// ---------------------------------------------------------------------------
__global__ __launch_bounds__(256) void fused_stage1_kernel(
    const float* __restrict__ x, const int* __restrict__ am,
    const unsigned int* __restrict__ spans_raw,
    float* __restrict__ Pf, int* __restrict__ Pam, int* __restrict__ dec) {
    const int bc = blockIdx.x;

    if (bc < Bn * NSEG) {
        // ---- segment stream + intra-segment prefix, skipping w==0 rows ----
        const int b = bc / NSEG;
        const int seg = bc % NSEG;
        const int d0 = threadIdx.x * 4;

        const float* xp = x + ((size_t)b * Ln + (size_t)seg * SEGTOK) * Dn + d0;
        const int* amp = am + b * Ln + seg * SEGTOK;
        float* pf = Pf + (size_t)bc * SLOTS * Dn + d0;

        float4 acc = {0.f, 0.f, 0.f, 0.f};
#pragma unroll
        for (int j = 0; j < CPS; ++j) {
            *(float4*)(pf + (size_t)j * Dn) = acc;   // exclusive prefix slot j
            int wv[CH];
#pragma unroll
            for (int t = 0; t < CH; ++t) wv[t] = amp[j * CH + t];
#pragma unroll
            for (int t = 0; t < CH; ++t) {
                if (wv[t] != 0) {        // uniform across lanes in practice
                    const int l = j * CH + t;
                    const float4 v = *(const float4*)(xp + (size_t)l * Dn);
                    acc4w(acc, v, (float)wv[t]);
                }
            }
        }
        *(float4*)(pf + (size_t)CPS * Dn) = acc;     // segment total
    } else if (bc < Bn * NSEG + Bn) {
        // ---- am token-prefix for batch b ----
        const int b = bc - Bn * NSEG;
        const int t = threadIdx.x;
        const int i0 = t * 16;
        const int* amb = am + (size_t)b * Ln;
        int loc[16];
        int lsum = 0;
#pragma unroll
        for (int j = 0; j < 16; ++j) { loc[j] = amb[i0 + j]; lsum += loc[j]; }

        __shared__ int ssum[256];
        ssum[t] = lsum;
        __syncthreads();
        for (int off = 1; off < 256; off <<= 1) {
            int v = (t >= off) ? ssum[t - off] : 0;
            __syncthreads();
            ssum[t] += v;
            __syncthreads();
        }
        int run = ssum[t] - lsum;                    // exclusive offset
        int* pam = Pam + (size_t)b * (Ln + 1);
#pragma unroll
        for (int j = 0; j < 16; ++j) { pam[i0 + j] = run; run += loc[j]; }
        if (t == 255) pam[Ln] = run;
    } else {
        // ---- span decode ----
        __shared__ unsigned int sred[256];
        unsigned int acc = 0;
        for (int i = threadIdx.x; i < NSPAN / 2; i += 256)
            acc |= spans_raw[2 * i + 1];
        sred[threadIdx.x] = acc;
        __syncthreads();
        for (int off = 128; off > 0; off >>= 1) {
            if ((int)threadIdx.x < off) sred[threadIdx.x] |= sred[threadIdx.x + off];
            __syncthreads();
        }
        const bool is64 = (sred[0] == 0u);
        for (int i = threadIdx.x; i < NSPAN; i += 256)
            dec[i] = is64 ? (int)spans_raw[2 * i] : (int)spans_raw[i];
    }
}

// ---------------------------------------------------------------------------
// K2: per-span pooling. grid = B*K blocks, 256 threads, no syncthreads.
// mask_sum = Pam[e]-Pam[s]. use_am interior: intra-seg prefix diffs +
// middle segment totals (L2/L3-resident Pf) + weighted ATTENDED edge rows
// from x. !use_am (rare, tiny spans only): direct plain-mean loop.
// ---------------------------------------------------------------------------
__global__ __launch_bounds__(256) void span_pool_kernel(
    const float* __restrict__ x, const int* __restrict__ am,
    const int* __restrict__ spans, const float* __restrict__ Pf,
    const int* __restrict__ Pam, float* __restrict__ H,
    float* __restrict__ sent_mask) {
    const int bk = blockIdx.x;          // b*K + k
    const int b = bk / Kn;

    int s = spans[2 * bk];
    int e = spans[2 * bk + 1];
    if (s < 0) s = 0; if (s > Ln) s = Ln;
    if (e < 0) e = 0; if (e > Ln) e = Ln;
    const int len = (e > s) ? (e - s) : 0;
    if (e < s) e = s;

    const int* pam = Pam + (size_t)b * (Ln + 1);
    const int msum = pam[e] - pam[s];
    const bool use_am = (msum > 0);
    const bool valid = (len > 0);

    const int d0 = threadIdx.x * 4;
    const float* xb = x + (size_t)b * Ln * Dn + d0;
    const int* amb = am + (size_t)b * Ln;
    float4 acc = {0.f, 0.f, 0.f, 0.f};

    if (!use_am) {
        // rare: no attended tokens in span -> plain mean over [s,e)
        for (int l = s; l < e; ++l)
            acc4(acc, *(const float4*)(xb + (size_t)l * Dn));
    } else {
        // interior fine-chunk range [ca, cb); edges [s,e1hi) and [e2lo,e)
        const int ca = (s + CH - 1) / CH;
        const int cb = e / CH;
        int e1hi, e2lo, e2hi;
        if (ca <= cb) { e1hi = ca * CH; e2lo = cb * CH; e2hi = e; }
        else          { e1hi = e;       e2lo = 0;       e2hi = 0; }

        if (cb > ca) {
            const float* Pb = Pf + (size_t)b * NSEG * SLOTS * Dn + d0;
            const int sa = ca / CPS, ja = ca % CPS;
            const int sb = cb / CPS, jb = cb % CPS;
            if (sa == sb) {
                acc = *(const float4*)(Pb + (size_t)(sa * SLOTS + jb) * Dn);
                sub4(acc, *(const float4*)(Pb + (size_t)(sa * SLOTS + ja) * Dn));
            } else {
                // rest of segment sa
                acc = *(const float4*)(Pb + (size_t)(sa * SLOTS + CPS) * Dn);
                sub4(acc, *(const float4*)(Pb + (size_t)(sa * SLOTS + ja) * Dn));
                // full middle segments (2-way unrolled, independent chains)
                float4 m0 = {0.f,0.f,0.f,0.f}, m1 = {0.f,0.f,0.f,0.f};
                int ss = sa + 1;
                for (; ss + 1 < sb; ss += 2) {
                    acc4(m0, *(const float4*)(Pb + (size_t)(ss * SLOTS + CPS) * Dn));
                    acc4(m1, *(const float4*)(Pb + (size_t)((ss + 1) * SLOTS + CPS) * Dn));
                }
                if (ss < sb)
                    acc4(m0, *(const float4*)(Pb + (size_t)(ss * SLOTS + CPS) * Dn));
                acc4(acc, m0); acc4(acc, m1);
                // leading part of segment sb (sb==NSEG only when jb==0)
                if (jb > 0)
                    acc4(acc, *(const float4*)(Pb + (size_t)(sb * SLOTS + jb) * Dn));
            }
        }

        for (int l = s; l < e1hi; ++l) {
            const float w = (float)amb[l];
            if (w != 0.f) acc4w(acc, *(const float4*)(xb + (size_t)l * Dn), w);
        }
        for (int l = e2lo; l < e2hi; ++l) {
            const float w = (float)amb[l];
            if (w != 0.f) acc4w(acc, *(const float4*)(xb + (size_t)l * Dn), w);
        }
    }

    const float denom = use_am ? (float)msum : (float)len;
    const float inv = valid ? (1.0f / denom) : 0.0f;
    float4 outv;
    outv.x = acc.x * inv; outv.y = acc.y * inv;
    outv.z = acc.z * inv; outv.w = acc.w * inv;

    *(float4*)(H + (size_t)bk * Dn + d0) = outv;
    if (threadIdx.x == 0) sent_mask[bk] = valid ? 1.0f : 0.0f;
}

extern "C" void kernel_launch(void* const* d_in, const int* in_sizes, int n_in,
                              void* d_out, int out_size, void* d_ws, size_t ws_size,
                              hipStream_t stream) {
    const float* x = (const float*)d_in[0];
    const int* am = (const int*)d_in[1];
    const unsigned int* spans_raw = (const unsigned int*)d_in[2];

    float* H = (float*)d_out;
    float* sent_mask = H + (size_t)Bn * Kn * Dn;

    // workspace layout: dec | Pam | Pf
    const size_t dec_bytes = 8192;                                 // >= NSPAN*4
    const size_t pam_bytes = (size_t)Bn * (Ln + 1) * sizeof(int);  // 262 KB
    int* dec = (int*)d_ws;
    int* Pam = (int*)((char*)d_ws + dec_bytes);
    float* Pf = (float*)((char*)d_ws + dec_bytes + pam_bytes + 192); // ~25 MB, 16B-aligned

    fused_stage1_kernel<<<Bn * NSEG + Bn + 1, 256, 0, stream>>>(
        x, am, spans_raw, Pf, Pam, dec);
    span_pool_kernel<<<Bn * Kn, 256, 0, stream>>>(
        x, am, dec, Pf, Pam, H, sent_mask);
}

// Round 10
// 41.521 us; speedup vs baseline: 1.4451x; 1.4451x over previous
//
#include <hip/hip_runtime.h>

// Problem constants (from reference): B=16, L=4096, D=1024, K=64
#define Bn 16
#define Ln 4096
#define Dn 1024
#define Kn 64
#define CH 16                  // tokens per fine chunk (slot granularity)
#define SEGTOK 128             // tokens per segment (one stream block)
#define CPS (SEGTOK / CH)      // 8 chunks per segment
#define NSEG (Ln / SEGTOK)     // 32 segments per batch row
#define SLOTS (CPS + 1)        // 9 slots: excl prefix at chunk j, slot 8 = seg total
#define NSPAN (2 * Bn * Kn)    // 2048 span ints

static __device__ __forceinline__ void acc4(float4& a, const float4 v) {
    a.x += v.x; a.y += v.y; a.z += v.z; a.w += v.w;
}
static __device__ __forceinline__ void sub4(float4& a, const float4 v) {
    a.x -= v.x; a.y -= v.y; a.z -= v.z; a.w -= v.w;
}
static __device__ __forceinline__ void acc4w(float4& a, const float4 v, float w) {
    a.x += v.x * w; a.y += v.y * w; a.z += v.z * w; a.w += v.w * w;
}

// ---------------------------------------------------------------------------
// K1 (fused stream + scan, BRANCH-FREE weighted loads): grid = B*NSEG
// segment blocks + B am-prefix blocks + 1 decode block.
//  - segment blocks: per 16-token chunk, compute effective index
//    le[t] = last attended token index <= t (pure cndmask chain), then
//    issue all 16 row loads UNCONDITIONALLY (duplicates of already-loaded
//    rows hit L1/L2 -> no extra HBM traffic) and FMA with weight w[t]
//    (w=0 zeroes the duplicate contributions, matching the reference's
//    multiply-by-zero semantics exactly). No data-dependent branches in
//    the load path -> loads batch and pipeline at full depth.
//    Running weighted sum written as exclusive intra-segment prefix every
//    16 tokens (slots 0..7) + segment total (slot 8).
//  - am-prefix blocks: exclusive token prefix of attention_mask per batch.
//  - decode block: canonicalize sent_spans to int32 (int64 layout detect).
// ---------------------------------------------------------------------------
__global__ __launch_bounds__(256) void fused_stage1_kernel(
    const float* __restrict__ x, const int* __restrict__ am,
    const unsigned int* __restrict__ spans_raw,
    float* __restrict__ Pf, int* __restrict__ Pam, int* __restrict__ dec) {
    const int bc = blockIdx.x;

    if (bc < Bn * NSEG) {
        // ---- segment stream + intra-segment prefix ----
        const int b = bc / NSEG;
        const int seg = bc % NSEG;
        const int d0 = threadIdx.x * 4;

        const float* xp = x + ((size_t)b * Ln + (size_t)seg * SEGTOK) * Dn + d0;
        const int* amp = am + b * Ln + seg * SEGTOK;
        float* pf = Pf + (size_t)bc * SLOTS * Dn + d0;

        float4 acc = {0.f, 0.f, 0.f, 0.f};
        for (int j = 0; j < CPS; ++j) {
            *(float4*)(pf + (size_t)j * Dn) = acc;   // exclusive prefix slot j

            int wv[CH];
#pragma unroll
            for (int t = 0; t < CH; ++t) wv[t] = amp[j * CH + t];

            int any = 0;
#pragma unroll
            for (int t = 0; t < CH; ++t) any |= wv[t];

            if (any != 0) {                          // uniform in practice
                // first attended index in chunk (unrolled select chain)
                int f = 0;
#pragma unroll
                for (int t = CH - 1; t >= 0; --t) if (wv[t] != 0) f = t;
                // effective index: last attended <= t (self if attended)
                int le[CH];
                int lp = f;
#pragma unroll
                for (int t = 0; t < CH; ++t) {
                    lp = (wv[t] != 0) ? t : lp;
                    le[t] = lp;
                }
                // branch-free load batch + weighted FMA (dual accumulators)
                float4 v[CH];
#pragma unroll
                for (int t = 0; t < CH; ++t)
                    v[t] = *(const float4*)(xp + (size_t)(j * CH + le[t]) * Dn);
                float4 s0 = {0.f, 0.f, 0.f, 0.f}, s1 = {0.f, 0.f, 0.f, 0.f};
#pragma unroll
                for (int t = 0; t < CH; t += 2) {
                    acc4w(s0, v[t],     (float)wv[t]);
                    acc4w(s1, v[t + 1], (float)wv[t + 1]);
                }
                acc4(s0, s1);
                acc4(acc, s0);
            }
        }
        *(float4*)(pf + (size_t)CPS * Dn) = acc;     // segment total
    } else if (bc < Bn * NSEG + Bn) {
        // ---- am token-prefix for batch b ----
        const int b = bc - Bn * NSEG;
        const int t = threadIdx.x;
        const int i0 = t * 16;
        const int* amb = am + (size_t)b * Ln;
        int loc[16];
        int lsum = 0;
#pragma unroll
        for (int j = 0; j < 16; ++j) { loc[j] = amb[i0 + j]; lsum += loc[j]; }

        __shared__ int ssum[256];
        ssum[t] = lsum;
        __syncthreads();
        for (int off = 1; off < 256; off <<= 1) {
            int v = (t >= off) ? ssum[t - off] : 0;
            __syncthreads();
            ssum[t] += v;
            __syncthreads();
        }
        int run = ssum[t] - lsum;                    // exclusive offset
        int* pam = Pam + (size_t)b * (Ln + 1);
#pragma unroll
        for (int j = 0; j < 16; ++j) { pam[i0 + j] = run; run += loc[j]; }
        if (t == 255) pam[Ln] = run;
    } else {
        // ---- span decode ----
        __shared__ unsigned int sred[256];
        unsigned int acc = 0;
        for (int i = threadIdx.x; i < NSPAN / 2; i += 256)
            acc |= spans_raw[2 * i + 1];
        sred[threadIdx.x] = acc;
        __syncthreads();
        for (int off = 128; off > 0; off >>= 1) {
            if ((int)threadIdx.x < off) sred[threadIdx.x] |= sred[threadIdx.x + off];
            __syncthreads();
        }
        const bool is64 = (sred[0] == 0u);
        for (int i = threadIdx.x; i < NSPAN; i += 256)
            dec[i] = is64 ? (int)spans_raw[2 * i] : (int)spans_raw[i];
    }
}

// ---------------------------------------------------------------------------
// K2: per-span pooling. grid = B*K blocks, 256 threads, no syncthreads.
// mask_sum = Pam[e]-Pam[s]. use_am interior: intra-seg prefix diffs +
// middle segment totals (L2/L3-resident Pf) + weighted ATTENDED edge rows
// from x. !use_am (rare, tiny spans only): direct plain-mean loop.
// ---------------------------------------------------------------------------
__global__ __launch_bounds__(256) void span_pool_kernel(
    const float* __restrict__ x, const int* __restrict__ am,
    const int* __restrict__ spans, const float* __restrict__ Pf,
    const int* __restrict__ Pam, float* __restrict__ H,
    float* __restrict__ sent_mask) {
    const int bk = blockIdx.x;          // b*K + k
    const int b = bk / Kn;

    int s = spans[2 * bk];
    int e = spans[2 * bk + 1];
    if (s < 0) s = 0; if (s > Ln) s = Ln;
    if (e < 0) e = 0; if (e > Ln) e = Ln;
    const int len = (e > s) ? (e - s) : 0;
    if (e < s) e = s;

    const int* pam = Pam + (size_t)b * (Ln + 1);
    const int msum = pam[e] - pam[s];
    const bool use_am = (msum > 0);
    const bool valid = (len > 0);

    const int d0 = threadIdx.x * 4;
    const float* xb = x + (size_t)b * Ln * Dn + d0;
    const int* amb = am + (size_t)b * Ln;
    float4 acc = {0.f, 0.f, 0.f, 0.f};

    if (!use_am) {
        // rare: no attended tokens in span -> plain mean over [s,e)
        for (int l = s; l < e; ++l)
            acc4(acc, *(const float4*)(xb + (size_t)l * Dn));
    } else {
        // interior fine-chunk range [ca, cb); edges [s,e1hi) and [e2lo,e)
        const int ca = (s + CH - 1) / CH;
        const int cb = e / CH;
        int e1hi, e2lo, e2hi;
        if (ca <= cb) { e1hi = ca * CH; e2lo = cb * CH; e2hi = e; }
        else          { e1hi = e;       e2lo = 0;       e2hi = 0; }

        if (cb > ca) {
            const float* Pb = Pf + (size_t)b * NSEG * SLOTS * Dn + d0;
            const int sa = ca / CPS, ja = ca % CPS;
            const int sb = cb / CPS, jb = cb % CPS;
            if (sa == sb) {
                acc = *(const float4*)(Pb + (size_t)(sa * SLOTS + jb) * Dn);
                sub4(acc, *(const float4*)(Pb + (size_t)(sa * SLOTS + ja) * Dn));
            } else {
                // rest of segment sa
                acc = *(const float4*)(Pb + (size_t)(sa * SLOTS + CPS) * Dn);
                sub4(acc, *(const float4*)(Pb + (size_t)(sa * SLOTS + ja) * Dn));
                // full middle segments (2-way unrolled, independent chains)
                float4 m0 = {0.f,0.f,0.f,0.f}, m1 = {0.f,0.f,0.f,0.f};
                int ss = sa + 1;
                for (; ss + 1 < sb; ss += 2) {
                    acc4(m0, *(const float4*)(Pb + (size_t)(ss * SLOTS + CPS) * Dn));
                    acc4(m1, *(const float4*)(Pb + (size_t)((ss + 1) * SLOTS + CPS) * Dn));
                }
                if (ss < sb)
                    acc4(m0, *(const float4*)(Pb + (size_t)(ss * SLOTS + CPS) * Dn));
                acc4(acc, m0); acc4(acc, m1);
                // leading part of segment sb (sb==NSEG only when jb==0)
                if (jb > 0)
                    acc4(acc, *(const float4*)(Pb + (size_t)(sb * SLOTS + jb) * Dn));
            }
        }

        for (int l = s; l < e1hi; ++l) {
            const float w = (float)amb[l];
            if (w != 0.f) acc4w(acc, *(const float4*)(xb + (size_t)l * Dn), w);
        }
        for (int l = e2lo; l < e2hi; ++l) {
            const float w = (float)amb[l];
            if (w != 0.f) acc4w(acc, *(const float4*)(xb + (size_t)l * Dn), w);
        }
    }

    const float denom = use_am ? (float)msum : (float)len;
    const float inv = valid ? (1.0f / denom) : 0.0f;
    float4 outv;
    outv.x = acc.x * inv; outv.y = acc.y * inv;
    outv.z = acc.z * inv; outv.w = acc.w * inv;

    *(float4*)(H + (size_t)bk * Dn + d0) = outv;
    if (threadIdx.x == 0) sent_mask[bk] = valid ? 1.0f : 0.0f;
}

extern "C" void kernel_launch(void* const* d_in, const int* in_sizes, int n_in,
                              void* d_out, int out_size, void* d_ws, size_t ws_size,
                              hipStream_t stream) {
    const float* x = (const float*)d_in[0];
    const int* am = (const int*)d_in[1];
    const unsigned int* spans_raw = (const unsigned int*)d_in[2];

    float* H = (float*)d_out;
    float* sent_mask = H + (size_t)Bn * Kn * Dn;

    // workspace layout: dec | Pam | Pf
    const size_t dec_bytes = 8192;                                 // >= NSPAN*4
    const size_t pam_bytes = (size_t)Bn * (Ln + 1) * sizeof(int);  // 262208 B
    int* dec = (int*)d_ws;
    int* Pam = (int*)((char*)d_ws + dec_bytes);
    float* Pf = (float*)((char*)d_ws + dec_bytes + pam_bytes);     // ~18.9 MB

    fused_stage1_kernel<<<Bn * NSEG + Bn + 1, 256, 0, stream>>>(
        x, am, spans_raw, Pf, Pam, dec);
    span_pool_kernel<<<Bn * Kn, 256, 0, stream>>>(
        x, am, dec, Pf, Pam, H, sent_mask);
}

// Round 11
// 40.337 us; speedup vs baseline: 1.4875x; 1.0294x over previous
//
#include <hip/hip_runtime.h>

// Problem constants (from reference): B=16, L=4096, D=1024, K=64
#define Bn 16
#define Ln 4096
#define Dn 1024
#define Kn 64
#define CH 16                  // tokens per fine chunk (slot granularity)
#define SEGTOK 128             // tokens per segment (one stream block)
#define CPS (SEGTOK / CH)      // 8 chunks per segment
#define NSEG (Ln / SEGTOK)     // 32 segments per batch row
#define SLOTS (CPS + 1)        // 9 slots: excl prefix at chunk j, slot 8 = seg total
#define NSPAN (2 * Bn * Kn)    // 2048 span ints

static __device__ __forceinline__ void acc4(float4& a, const float4 v) {
    a.x += v.x; a.y += v.y; a.z += v.z; a.w += v.w;
}
static __device__ __forceinline__ void sub4(float4& a, const float4 v) {
    a.x -= v.x; a.y -= v.y; a.z -= v.z; a.w -= v.w;
}
static __device__ __forceinline__ void acc4w(float4& a, const float4 v, float w) {
    a.x += v.x * w; a.y += v.y * w; a.z += v.z * w; a.w += v.w * w;
}

// ---------------------------------------------------------------------------
// K1 (fused stream + scan, BRANCH-FREE weighted loads): grid = B*NSEG
// segment blocks + B am-prefix blocks + 1 decode block. See R10 notes:
// effective-index le[t] (last attended <= t) makes all 16 row loads per
// chunk unconditional (duplicates hit L1), weight 0 kills duplicates.
// ---------------------------------------------------------------------------
__global__ __launch_bounds__(256) void fused_stage1_kernel(
    const float* __restrict__ x, const int* __restrict__ am,
    const unsigned int* __restrict__ spans_raw,
    float* __restrict__ Pf, int* __restrict__ Pam, int* __restrict__ dec) {
    const int bc = blockIdx.x;

    if (bc < Bn * NSEG) {
        // ---- segment stream + intra-segment prefix ----
        const int b = bc / NSEG;
        const int seg = bc % NSEG;
        const int d0 = threadIdx.x * 4;

        const float* xp = x + ((size_t)b * Ln + (size_t)seg * SEGTOK) * Dn + d0;
        const int* amp = am + b * Ln + seg * SEGTOK;
        float* pf = Pf + (size_t)bc * SLOTS * Dn + d0;

        float4 acc = {0.f, 0.f, 0.f, 0.f};
        for (int j = 0; j < CPS; ++j) {
            *(float4*)(pf + (size_t)j * Dn) = acc;   // exclusive prefix slot j

            int wv[CH];
#pragma unroll
            for (int t = 0; t < CH; ++t) wv[t] = amp[j * CH + t];

            int any = 0;
#pragma unroll
            for (int t = 0; t < CH; ++t) any |= wv[t];

            if (any != 0) {                          // uniform in practice
                int f = 0;
#pragma unroll
                for (int t = CH - 1; t >= 0; --t) if (wv[t] != 0) f = t;
                int le[CH];
                int lp = f;
#pragma unroll
                for (int t = 0; t < CH; ++t) {
                    lp = (wv[t] != 0) ? t : lp;
                    le[t] = lp;
                }
                float4 v[CH];
#pragma unroll
                for (int t = 0; t < CH; ++t)
                    v[t] = *(const float4*)(xp + (size_t)(j * CH + le[t]) * Dn);
                float4 s0 = {0.f, 0.f, 0.f, 0.f}, s1 = {0.f, 0.f, 0.f, 0.f};
#pragma unroll
                for (int t = 0; t < CH; t += 2) {
                    acc4w(s0, v[t],     (float)wv[t]);
                    acc4w(s1, v[t + 1], (float)wv[t + 1]);
                }
                acc4(s0, s1);
                acc4(acc, s0);
            }
        }
        *(float4*)(pf + (size_t)CPS * Dn) = acc;     // segment total
    } else if (bc < Bn * NSEG + Bn) {
        // ---- am token-prefix for batch b ----
        const int b = bc - Bn * NSEG;
        const int t = threadIdx.x;
        const int i0 = t * 16;
        const int* amb = am + (size_t)b * Ln;
        int loc[16];
        int lsum = 0;
#pragma unroll
        for (int j = 0; j < 16; ++j) { loc[j] = amb[i0 + j]; lsum += loc[j]; }

        __shared__ int ssum[256];
        ssum[t] = lsum;
        __syncthreads();
        for (int off = 1; off < 256; off <<= 1) {
            int v = (t >= off) ? ssum[t - off] : 0;
            __syncthreads();
            ssum[t] += v;
            __syncthreads();
        }
        int run = ssum[t] - lsum;                    // exclusive offset
        int* pam = Pam + (size_t)b * (Ln + 1);
#pragma unroll
        for (int j = 0; j < 16; ++j) { pam[i0 + j] = run; run += loc[j]; }
        if (t == 255) pam[Ln] = run;
    } else {
        // ---- span decode ----
        __shared__ unsigned int sred[256];
        unsigned int acc = 0;
        for (int i = threadIdx.x; i < NSPAN / 2; i += 256)
            acc |= spans_raw[2 * i + 1];
        sred[threadIdx.x] = acc;
        __syncthreads();
        for (int off = 128; off > 0; off >>= 1) {
            if ((int)threadIdx.x < off) sred[threadIdx.x] |= sred[threadIdx.x + off];
            __syncthreads();
        }
        const bool is64 = (sred[0] == 0u);
        for (int i = threadIdx.x; i < NSPAN; i += 256)
            dec[i] = is64 ? (int)spans_raw[2 * i] : (int)spans_raw[i];
    }
}

// ---------------------------------------------------------------------------
// K2: per-span pooling. grid = B*K blocks, 256 threads, no syncthreads.
// mask_sum = Pam[e]-Pam[s]. use_am interior: intra-seg prefix diffs +
// middle segment totals. Edge token ranges use the same BRANCH-FREE
// effective-index pattern as K1: fixed 16-slot unrolled block, masked
// weights, unconditional loads (dups -> L1 hits), w=0 kills duplicates.
// ---------------------------------------------------------------------------
__global__ __launch_bounds__(256) void span_pool_kernel(
    const float* __restrict__ x, const int* __restrict__ am,
    const int* __restrict__ spans, const float* __restrict__ Pf,
    const int* __restrict__ Pam, float* __restrict__ H,
    float* __restrict__ sent_mask) {
    const int bk = blockIdx.x;          // b*K + k
    const int b = bk / Kn;

    int s = spans[2 * bk];
    int e = spans[2 * bk + 1];
    if (s < 0) s = 0; if (s > Ln) s = Ln;
    if (e < 0) e = 0; if (e > Ln) e = Ln;
    const int len = (e > s) ? (e - s) : 0;
    if (e < s) e = s;

    const int* pam = Pam + (size_t)b * (Ln + 1);
    const int msum = pam[e] - pam[s];
    const bool use_am = (msum > 0);
    const bool valid = (len > 0);

    const int d0 = threadIdx.x * 4;
    const float* xb = x + (size_t)b * Ln * Dn + d0;
    const int* amb = am + (size_t)b * Ln;
    float4 acc = {0.f, 0.f, 0.f, 0.f};

    if (!use_am) {
        // rare: no attended tokens in span -> plain mean over [s,e)
        for (int l = s; l < e; ++l)
            acc4(acc, *(const float4*)(xb + (size_t)l * Dn));
    } else {
        // interior fine-chunk range [ca, cb); edges [s,e1hi) and [e2lo,e)
        const int ca = (s + CH - 1) / CH;
        const int cb = e / CH;
        int e1hi, e2lo, e2hi;
        if (ca <= cb) { e1hi = ca * CH; e2lo = cb * CH; e2hi = e; }
        else          { e1hi = e;       e2lo = 0;       e2hi = 0; }

        if (cb > ca) {
            const float* Pb = Pf + (size_t)b * NSEG * SLOTS * Dn + d0;
            const int sa = ca / CPS, ja = ca % CPS;
            const int sb = cb / CPS, jb = cb % CPS;
            if (sa == sb) {
                acc = *(const float4*)(Pb + (size_t)(sa * SLOTS + jb) * Dn);
                sub4(acc, *(const float4*)(Pb + (size_t)(sa * SLOTS + ja) * Dn));
            } else {
                acc = *(const float4*)(Pb + (size_t)(sa * SLOTS + CPS) * Dn);
                sub4(acc, *(const float4*)(Pb + (size_t)(sa * SLOTS + ja) * Dn));
                float4 m0 = {0.f,0.f,0.f,0.f}, m1 = {0.f,0.f,0.f,0.f};
                int ss = sa + 1;
                for (; ss + 1 < sb; ss += 2) {
                    acc4(m0, *(const float4*)(Pb + (size_t)(ss * SLOTS + CPS) * Dn));
                    acc4(m1, *(const float4*)(Pb + (size_t)((ss + 1) * SLOTS + CPS) * Dn));
                }
                if (ss < sb)
                    acc4(m0, *(const float4*)(Pb + (size_t)(ss * SLOTS + CPS) * Dn));
                acc4(acc, m0); acc4(acc, m1);
                if (jb > 0)
                    acc4(acc, *(const float4*)(Pb + (size_t)(sb * SLOTS + jb) * Dn));
            }
        }

        // ---- branch-free edge sides (base, elen < 16 each) ----
#pragma unroll
        for (int side = 0; side < 2; ++side) {
            const int base = side ? e2lo : s;
            const int elen = side ? (e2hi - e2lo) : (e1hi - s);
            if (elen > 0) {
                int wv[CH];
#pragma unroll
                for (int t = 0; t < CH; ++t) {
                    const int li = (base + t < Ln) ? (base + t) : (Ln - 1);
                    wv[t] = (t < elen) ? amb[li] : 0;
                }
                int any = 0;
#pragma unroll
                for (int t = 0; t < CH; ++t) any |= wv[t];
                if (any != 0) {
                    int f = 0;
#pragma unroll
                    for (int t = CH - 1; t >= 0; --t) if (wv[t] != 0) f = t;
                    int le[CH];
                    int lp = f;
#pragma unroll
                    for (int t = 0; t < CH; ++t) {
                        lp = (wv[t] != 0) ? t : lp;
                        le[t] = lp;
                    }
                    float4 v[CH];
#pragma unroll
                    for (int t = 0; t < CH; ++t)
                        v[t] = *(const float4*)(xb + (size_t)(base + le[t]) * Dn);
                    float4 s0 = {0.f,0.f,0.f,0.f}, s1 = {0.f,0.f,0.f,0.f};
#pragma unroll
                    for (int t = 0; t < CH; t += 2) {
                        acc4w(s0, v[t],     (float)wv[t]);
                        acc4w(s1, v[t + 1], (float)wv[t + 1]);
                    }
                    acc4(s0, s1);
                    acc4(acc, s0);
                }
            }
        }
    }

    const float denom = use_am ? (float)msum : (float)len;
    const float inv = valid ? (1.0f / denom) : 0.0f;
    float4 outv;
    outv.x = acc.x * inv; outv.y = acc.y * inv;
    outv.z = acc.z * inv; outv.w = acc.w * inv;

    *(float4*)(H + (size_t)bk * Dn + d0) = outv;
    if (threadIdx.x == 0) sent_mask[bk] = valid ? 1.0f : 0.0f;
}

extern "C" void kernel_launch(void* const* d_in, const int* in_sizes, int n_in,
                              void* d_out, int out_size, void* d_ws, size_t ws_size,
                              hipStream_t stream) {
    const float* x = (const float*)d_in[0];
    const int* am = (const int*)d_in[1];
    const unsigned int* spans_raw = (const unsigned int*)d_in[2];

    float* H = (float*)d_out;
    float* sent_mask = H + (size_t)Bn * Kn * Dn;

    // workspace layout: dec | Pam | Pf
    const size_t dec_bytes = 8192;                                 // >= NSPAN*4
    const size_t pam_bytes = (size_t)Bn * (Ln + 1) * sizeof(int);  // 262208 B
    int* dec = (int*)d_ws;
    int* Pam = (int*)((char*)d_ws + dec_bytes);
    float* Pf = (float*)((char*)d_ws + dec_bytes + pam_bytes);     // ~18.9 MB

    fused_stage1_kernel<<<Bn * NSEG + Bn + 1, 256, 0, stream>>>(
        x, am, spans_raw, Pf, Pam, dec);
    span_pool_kernel<<<Bn * Kn, 256, 0, stream>>>(
        x, am, dec, Pf, Pam, H, sent_mask);
}

// Round 12
// 40.237 us; speedup vs baseline: 1.4912x; 1.0025x over previous
//
#include <hip/hip_runtime.h>

// Problem constants (from reference): B=16, L=4096, D=1024, K=64
#define Bn 16
#define Ln 4096
#define Dn 1024
#define Kn 64
#define CH 16                  // tokens per fine chunk (slot granularity)
#define SEGTOK 128             // tokens per segment (one stream block)
#define CPS (SEGTOK / CH)      // 8 chunks per segment
#define NSEG (Ln / SEGTOK)     // 32 segments per batch row
#define SLOTS (CPS + 1)        // 9 slots: excl prefix at chunk j, slot 8 = seg total
#define NSPAN (2 * Bn * Kn)    // 2048 span ints

static __device__ __forceinline__ void acc4(float4& a, const float4 v) {
    a.x += v.x; a.y += v.y; a.z += v.z; a.w += v.w;
}
static __device__ __forceinline__ void sub4(float4& a, const float4 v) {
    a.x -= v.x; a.y -= v.y; a.z -= v.z; a.w -= v.w;
}
static __device__ __forceinline__ void acc4w(float4& a, const float4 v, float w) {
    a.x += v.x * w; a.y += v.y * w; a.z += v.z * w; a.w += v.w * w;
}

// ---------------------------------------------------------------------------
// K1 (fused stream + scan, FULLY BRANCH-FREE + software-pipelined):
// grid = B*NSEG segment blocks + B am-prefix blocks + 1 decode block.
//  - segment blocks: per 16-token chunk, effective index le[t] = last
//    attended token <= t (cndmask chain; all-zero chunk degenerates to
//    le[t]=0 with all weights 0 -> exact no-op, no branch needed).
//    Chunk j+1's am-prep and 16 row loads are ISSUED BEFORE chunk j's
//    FMAs consume its data (manual double buffer, static indexing via
//    full unroll) so HBM latency pipelines across chunks.
//  - am-prefix blocks: exclusive token prefix of attention_mask per batch.
//  - decode block: canonicalize sent_spans to int32 (int64 layout detect).
// ---------------------------------------------------------------------------
__global__ __launch_bounds__(256) void fused_stage1_kernel(
    const float* __restrict__ x, const int* __restrict__ am,
    const unsigned int* __restrict__ spans_raw,
    float* __restrict__ Pf, int* __restrict__ Pam, int* __restrict__ dec) {
    const int bc = blockIdx.x;

    if (bc < Bn * NSEG) {
        // ---- segment stream + intra-segment prefix ----
        const int b = bc / NSEG;
        const int seg = bc % NSEG;
        const int d0 = threadIdx.x * 4;

        const float* xp = x + ((size_t)b * Ln + (size_t)seg * SEGTOK) * Dn + d0;
        const int* amp = am + b * Ln + seg * SEGTOK;
        float* pf = Pf + (size_t)bc * SLOTS * Dn + d0;

        int   wv[2][CH];
        float4 v[2][CH];

        // prologue: prep + issue loads for chunk 0 into buffer 0
        {
            int lw[CH];
#pragma unroll
            for (int t = 0; t < CH; ++t) lw[t] = amp[t];
            int f = 0;
#pragma unroll
            for (int t = CH - 1; t >= 0; --t) if (lw[t] != 0) f = t;
            int lp = f;
#pragma unroll
            for (int t = 0; t < CH; ++t) {
                lp = (lw[t] != 0) ? t : lp;
                v[0][t] = *(const float4*)(xp + (size_t)lp * Dn);
                wv[0][t] = lw[t];
            }
        }

        float4 acc = {0.f, 0.f, 0.f, 0.f};
#pragma unroll
        for (int j = 0; j < CPS; ++j) {
            const int cur = j & 1;
            const int nxt = cur ^ 1;

            // issue next chunk's loads before consuming current chunk
            if (j + 1 < CPS) {
                int lw[CH];
#pragma unroll
                for (int t = 0; t < CH; ++t) lw[t] = amp[(j + 1) * CH + t];
                int f = 0;
#pragma unroll
                for (int t = CH - 1; t >= 0; --t) if (lw[t] != 0) f = t;
                int lp = f;
#pragma unroll
                for (int t = 0; t < CH; ++t) {
                    lp = (lw[t] != 0) ? t : lp;
                    v[nxt][t] = *(const float4*)(xp + (size_t)((j + 1) * CH + lp) * Dn);
                    wv[nxt][t] = lw[t];
                }
            }

            *(float4*)(pf + (size_t)j * Dn) = acc;   // exclusive prefix slot j

            float4 s0 = {0.f, 0.f, 0.f, 0.f}, s1 = {0.f, 0.f, 0.f, 0.f};
#pragma unroll
            for (int t = 0; t < CH; t += 2) {
                acc4w(s0, v[cur][t],     (float)wv[cur][t]);
                acc4w(s1, v[cur][t + 1], (float)wv[cur][t + 1]);
            }
            acc4(s0, s1);
            acc4(acc, s0);
        }
        *(float4*)(pf + (size_t)CPS * Dn) = acc;     // segment total
    } else if (bc < Bn * NSEG + Bn) {
        // ---- am token-prefix for batch b ----
        const int b = bc - Bn * NSEG;
        const int t = threadIdx.x;
        const int i0 = t * 16;
        const int* amb = am + (size_t)b * Ln;
        int loc[16];
        int lsum = 0;
#pragma unroll
        for (int j = 0; j < 16; ++j) { loc[j] = amb[i0 + j]; lsum += loc[j]; }

        __shared__ int ssum[256];
        ssum[t] = lsum;
        __syncthreads();
        for (int off = 1; off < 256; off <<= 1) {
            int v2 = (t >= off) ? ssum[t - off] : 0;
            __syncthreads();
            ssum[t] += v2;
            __syncthreads();
        }
        int run = ssum[t] - lsum;                    // exclusive offset
        int* pam = Pam + (size_t)b * (Ln + 1);
#pragma unroll
        for (int j = 0; j < 16; ++j) { pam[i0 + j] = run; run += loc[j]; }
        if (t == 255) pam[Ln] = run;
    } else {
        // ---- span decode ----
        __shared__ unsigned int sred[256];
        unsigned int acc = 0;
        for (int i = threadIdx.x; i < NSPAN / 2; i += 256)
            acc |= spans_raw[2 * i + 1];
        sred[threadIdx.x] = acc;
        __syncthreads();
        for (int off = 128; off > 0; off >>= 1) {
            if ((int)threadIdx.x < off) sred[threadIdx.x] |= sred[threadIdx.x + off];
            __syncthreads();
        }
        const bool is64 = (sred[0] == 0u);
        for (int i = threadIdx.x; i < NSPAN; i += 256)
            dec[i] = is64 ? (int)spans_raw[2 * i] : (int)spans_raw[i];
    }
}

// ---------------------------------------------------------------------------
// K2: per-span pooling. grid = B*K blocks, 256 threads, no syncthreads.
// mask_sum = Pam[e]-Pam[s]. use_am interior: intra-seg prefix diffs +
// middle segment totals. Edge token ranges use the branch-free
// effective-index pattern (fixed 16-slot unrolled block, masked weights,
// unconditional loads; w=0 kills duplicates).
// ---------------------------------------------------------------------------
__global__ __launch_bounds__(256) void span_pool_kernel(
    const float* __restrict__ x, const int* __restrict__ am,
    const int* __restrict__ spans, const float* __restrict__ Pf,
    const int* __restrict__ Pam, float* __restrict__ H,
    float* __restrict__ sent_mask) {
    const int bk = blockIdx.x;          // b*K + k
    const int b = bk / Kn;

    int s = spans[2 * bk];
    int e = spans[2 * bk + 1];
    if (s < 0) s = 0; if (s > Ln) s = Ln;
    if (e < 0) e = 0; if (e > Ln) e = Ln;
    const int len = (e > s) ? (e - s) : 0;
    if (e < s) e = s;

    const int* pam = Pam + (size_t)b * (Ln + 1);
    const int msum = pam[e] - pam[s];
    const bool use_am = (msum > 0);
    const bool valid = (len > 0);

    const int d0 = threadIdx.x * 4;
    const float* xb = x + (size_t)b * Ln * Dn + d0;
    const int* amb = am + (size_t)b * Ln;
    float4 acc = {0.f, 0.f, 0.f, 0.f};

    if (!use_am) {
        // rare: no attended tokens in span -> plain mean over [s,e)
        for (int l = s; l < e; ++l)
            acc4(acc, *(const float4*)(xb + (size_t)l * Dn));
    } else {
        // interior fine-chunk range [ca, cb); edges [s,e1hi) and [e2lo,e)
        const int ca = (s + CH - 1) / CH;
        const int cb = e / CH;
        int e1hi, e2lo, e2hi;
        if (ca <= cb) { e1hi = ca * CH; e2lo = cb * CH; e2hi = e; }
        else          { e1hi = e;       e2lo = 0;       e2hi = 0; }

        if (cb > ca) {
            const float* Pb = Pf + (size_t)b * NSEG * SLOTS * Dn + d0;
            const int sa = ca / CPS, ja = ca % CPS;
            const int sb = cb / CPS, jb = cb % CPS;
            if (sa == sb) {
                acc = *(const float4*)(Pb + (size_t)(sa * SLOTS + jb) * Dn);
                sub4(acc, *(const float4*)(Pb + (size_t)(sa * SLOTS + ja) * Dn));
            } else {
                acc = *(const float4*)(Pb + (size_t)(sa * SLOTS + CPS) * Dn);
                sub4(acc, *(const float4*)(Pb + (size_t)(sa * SLOTS + ja) * Dn));
                float4 m0 = {0.f,0.f,0.f,0.f}, m1 = {0.f,0.f,0.f,0.f};
                int ss = sa + 1;
                for (; ss + 1 < sb; ss += 2) {
                    acc4(m0, *(const float4*)(Pb + (size_t)(ss * SLOTS + CPS) * Dn));
                    acc4(m1, *(const float4*)(Pb + (size_t)((ss + 1) * SLOTS + CPS) * Dn));
                }
                if (ss < sb)
                    acc4(m0, *(const float4*)(Pb + (size_t)(ss * SLOTS + CPS) * Dn));
                acc4(acc, m0); acc4(acc, m1);
                if (jb > 0)
                    acc4(acc, *(const float4*)(Pb + (size_t)(sb * SLOTS + jb) * Dn));
            }
        }

        // ---- branch-free edge sides (base, elen < 16 each) ----
#pragma unroll
        for (int side = 0; side < 2; ++side) {
            const int base = side ? e2lo : s;
            const int elen = side ? (e2hi - e2lo) : (e1hi - s);
            if (elen > 0) {
                int wv[CH];
#pragma unroll
                for (int t = 0; t < CH; ++t) {
                    const int li = (base + t < Ln) ? (base + t) : (Ln - 1);
                    wv[t] = (t < elen) ? amb[li] : 0;
                }
                int any = 0;
#pragma unroll
                for (int t = 0; t < CH; ++t) any |= wv[t];
                if (any != 0) {
                    int f = 0;
#pragma unroll
                    for (int t = CH - 1; t >= 0; --t) if (wv[t] != 0) f = t;
                    int le[CH];
                    int lp = f;
#pragma unroll
                    for (int t = 0; t < CH; ++t) {
                        lp = (wv[t] != 0) ? t : lp;
                        le[t] = lp;
                    }
                    float4 v[CH];
#pragma unroll
                    for (int t = 0; t < CH; ++t)
                        v[t] = *(const float4*)(xb + (size_t)(base + le[t]) * Dn);
                    float4 s0 = {0.f,0.f,0.f,0.f}, s1 = {0.f,0.f,0.f,0.f};
#pragma unroll
                    for (int t = 0; t < CH; t += 2) {
                        acc4w(s0, v[t],     (float)wv[t]);
                        acc4w(s1, v[t + 1], (float)wv[t + 1]);
                    }
                    acc4(s0, s1);
                    acc4(acc, s0);
                }
            }
        }
    }

    const float denom = use_am ? (float)msum : (float)len;
    const float inv = valid ? (1.0f / denom) : 0.0f;
    float4 outv;
    outv.x = acc.x * inv; outv.y = acc.y * inv;
    outv.z = acc.z * inv; outv.w = acc.w * inv;

    *(float4*)(H + (size_t)bk * Dn + d0) = outv;
    if (threadIdx.x == 0) sent_mask[bk] = valid ? 1.0f : 0.0f;
}

extern "C" void kernel_launch(void* const* d_in, const int* in_sizes, int n_in,
                              void* d_out, int out_size, void* d_ws, size_t ws_size,
                              hipStream_t stream) {
    const float* x = (const float*)d_in[0];
    const int* am = (const int*)d_in[1];
    const unsigned int* spans_raw = (const unsigned int*)d_in[2];

    float* H = (float*)d_out;
    float* sent_mask = H + (size_t)Bn * Kn * Dn;

    // workspace layout: dec | Pam | Pf
    const size_t dec_bytes = 8192;                                 // >= NSPAN*4
    const size_t pam_bytes = (size_t)Bn * (Ln + 1) * sizeof(int);  // 262208 B
    int* dec = (int*)d_ws;
    int* Pam = (int*)((char*)d_ws + dec_bytes);
    float* Pf = (float*)((char*)d_ws + dec_bytes + pam_bytes);     // ~18.9 MB

    fused_stage1_kernel<<<Bn * NSEG + Bn + 1, 256, 0, stream>>>(
        x, am, spans_raw, Pf, Pam, dec);
    span_pool_kernel<<<Bn * Kn, 256, 0, stream>>>(
        x, am, dec, Pf, Pam, H, sent_mask);
}